// Round 1
// baseline (505.015 us; speedup 1.0000x reference)
//
#include <hip/hip_runtime.h>

// S = 256 everywhere. Out[b][D][q] = sum_k softmax_k(QK^T/16)[b,q,k]*keep[b,q,k]*v[b,k,D]
// qk_bias is a per-(b,q) additive constant before softmax -> softmax-invariant -> skipped.
// d_ws holds vT[b][D][k] as bf16: 256^3 * 2 = 33,554,432 bytes.

#define SDIM 256
#define LDSP 264  // padded LDS row stride (elements); 264*2=528B, 16B-aligned

typedef __bf16 bf16_t;
typedef __bf16 bf16x8 __attribute__((ext_vector_type(8)));
typedef __bf16 bf16x4 __attribute__((ext_vector_type(4)));
typedef float f32x4 __attribute__((ext_vector_type(4)));

__device__ inline bf16x8 cvt8(float4 a, float4 b) {
  bf16x8 r;
  r[0] = (bf16_t)a.x; r[1] = (bf16_t)a.y; r[2] = (bf16_t)a.z; r[3] = (bf16_t)a.w;
  r[4] = (bf16_t)b.x; r[5] = (bf16_t)b.y; r[6] = (bf16_t)b.z; r[7] = (bf16_t)b.w;
  return r;
}

// ---------------------------------------------------------------------------
// Kernel 1: vT[b][D][k] = sum_d W[b][d][D]*value[b][k][d] + v_bias[k][D], bf16
// grid = 256 b * 4 Dblocks; block = 256 (4 waves); wave w handles D rows
// [Dblk*64 + w*16, +16) x all 256 k.
// ---------------------------------------------------------------------------
__global__ __launch_bounds__(256) void vproj_kernel(
    const float* __restrict__ value, const float* __restrict__ v_weight,
    const float* __restrict__ v_bias, bf16_t* __restrict__ vT)
{
  __shared__ bf16_t WT[64 * LDSP];  // WT[c][r] = W[r][Dbase+c], bf16

  const int b     = blockIdx.x >> 2;
  const int Dblk  = blockIdx.x & 3;
  const int Dbase = Dblk * 64;
  const int t    = threadIdx.x;
  const int w    = t >> 6;
  const int lane = t & 63;
  const int lid  = lane & 15;
  const int quad = lane >> 4;

  const float* Wb = v_weight + (size_t)b * (SDIM * SDIM);
  const float* Vb = value    + (size_t)b * (SDIM * SDIM);

  // Stage W^T tile into LDS: read rows of W coalesced, write transposed.
  {
    const int c4 = (t & 15) * 4;   // col group within 64-wide D block
    const int r0 = t >> 4;         // 16 rows per pass
    for (int p = 0; p < 16; ++p) {
      const int r = p * 16 + r0;   // d index 0..255
      float4 f = *(const float4*)(Wb + r * SDIM + Dbase + c4);
      WT[(c4 + 0) * LDSP + r] = (bf16_t)f.x;
      WT[(c4 + 1) * LDSP + r] = (bf16_t)f.y;
      WT[(c4 + 2) * LDSP + r] = (bf16_t)f.z;
      WT[(c4 + 3) * LDSP + r] = (bf16_t)f.w;
    }
  }
  __syncthreads();

  // Cache A fragments (W^T rows for this wave's 16 D rows), all of d.
  bf16x8 af[8];
  #pragma unroll
  for (int d = 0; d < 8; ++d)
    af[d] = *(const bf16x8*)(&WT[(w * 16 + lid) * LDSP + d * 32 + quad * 8]);

  f32x4 acc[16];
  #pragma unroll
  for (int n = 0; n < 16; ++n) acc[n] = (f32x4){0.f, 0.f, 0.f, 0.f};

  // C'[D][k] = sum_d WT[D][d] * value[k][d]; B frags direct from global.
  #pragma unroll 4
  for (int n = 0; n < 16; ++n) {
    #pragma unroll
    for (int d = 0; d < 8; ++d) {
      const float* vp = Vb + (n * 16 + lid) * SDIM + d * 32 + quad * 8;
      float4 a = *(const float4*)(vp);
      float4 c = *(const float4*)(vp + 4);
      bf16x8 bfr = cvt8(a, c);
      acc[n] = __builtin_amdgcn_mfma_f32_16x16x32_bf16(af[d], bfr, acc[n], 0, 0, 0);
    }
  }

  // Epilogue: add bias (f32), convert, store vT rows (coalesced in k).
  bf16_t* outb = vT + (size_t)b * (SDIM * SDIM);
  #pragma unroll
  for (int n = 0; n < 16; ++n) {
    const int k = n * 16 + lid;
    #pragma unroll
    for (int j = 0; j < 4; ++j) {
      const int D = Dbase + w * 16 + quad * 4 + j;
      float v = acc[n][j] + v_bias[k * SDIM + D];
      outb[D * SDIM + k] = (bf16_t)v;
    }
  }
}

// ---------------------------------------------------------------------------
// Kernel 2: fused attention. grid = 256 b * 4 q-tiles; block = 256 (4 waves);
// wave w handles q rows [qt*64 + w*16, +16). Computes S = QK^T (K staged in
// LDS bf16), softmax in registers, dropout, P -> LDS (buffer reused), then
// out^T[D][q] = vT * P^T with coalesced f32 stores.
// ---------------------------------------------------------------------------
__global__ __launch_bounds__(256) void attn_kernel(
    const float* __restrict__ query, const float* __restrict__ key,
    const float* __restrict__ drop_u, const bf16_t* __restrict__ vT,
    float* __restrict__ out)
{
  __shared__ bf16_t KP[64 * LDSP];  // K tile (bf16), later reused for P

  const int b  = blockIdx.x >> 2;
  const int qt = blockIdx.x & 3;
  const int t    = threadIdx.x;
  const int w    = t >> 6;
  const int lane = t & 63;
  const int lid  = lane & 15;
  const int quad = lane >> 4;
  const int q0 = qt * 64 + w * 16;  // wave's q base

  const float* Qb = query + (size_t)b * (SDIM * SDIM);
  const float* Kb = key   + (size_t)b * (SDIM * SDIM);

  // Preload Q fragments (A-layout: row = q0+lid, k = d0 + quad*8 + j).
  bf16x8 qf[8];
  #pragma unroll
  for (int d = 0; d < 8; ++d) {
    const float* p = Qb + (q0 + lid) * SDIM + d * 32 + quad * 8;
    float4 a = *(const float4*)(p);
    float4 c = *(const float4*)(p + 4);
    qf[d] = cvt8(a, c);
  }

  f32x4 sacc[16];
  #pragma unroll
  for (int n = 0; n < 16; ++n) sacc[n] = (f32x4){0.f, 0.f, 0.f, 0.f};

  // Phase A: S[q][k] over 4 key tiles of 64 rows staged in LDS.
  for (int kt = 0; kt < 4; ++kt) {
    if (kt) __syncthreads();  // protect KP overwrite
    {
      const int r  = t >> 2;
      const int cb = t & 3;
      const float* src = Kb + (kt * 64 + r) * SDIM;
      #pragma unroll
      for (int i = 0; i < 16; ++i) {
        const int c4 = (cb + i * 4) * 4;
        float4 f = *(const float4*)(src + c4);
        bf16x4 h;
        h[0] = (bf16_t)f.x; h[1] = (bf16_t)f.y; h[2] = (bf16_t)f.z; h[3] = (bf16_t)f.w;
        *(bf16x4*)(&KP[r * LDSP + c4]) = h;
      }
    }
    __syncthreads();
    #pragma unroll
    for (int n4 = 0; n4 < 4; ++n4) {
      const int n = kt * 4 + n4;
      #pragma unroll
      for (int d = 0; d < 8; ++d) {
        bf16x8 bfr = *(const bf16x8*)(&KP[(n4 * 16 + lid) * LDSP + d * 32 + quad * 8]);
        sacc[n] = __builtin_amdgcn_mfma_f32_16x16x32_bf16(qf[d], bfr, sacc[n], 0, 0, 0);
      }
    }
  }
  __syncthreads();  // all waves done reading K before P overwrites KP

  // Softmax per q-row (row r = quad*4 + j lives in the 16 lanes of this quad).
  // Scale 1/16 folded into exp; qk_bias is softmax-invariant (skipped).
  #pragma unroll
  for (int j = 0; j < 4; ++j) {
    float mx = sacc[0][j];
    #pragma unroll
    for (int n = 1; n < 16; ++n) mx = fmaxf(mx, sacc[n][j]);
    #pragma unroll
    for (int off = 8; off >= 1; off >>= 1) mx = fmaxf(mx, __shfl_xor(mx, off, 64));
    float sum = 0.f;
    #pragma unroll
    for (int n = 0; n < 16; ++n) {
      float e = __expf((sacc[n][j] - mx) * 0.0625f);
      sacc[n][j] = e;
      sum += e;
    }
    #pragma unroll
    for (int off = 8; off >= 1; off >>= 1) sum += __shfl_xor(sum, off, 64);
    float inv = 1.0f / sum;
    #pragma unroll
    for (int n = 0; n < 16; ++n) sacc[n][j] *= inv;
  }

  // Dropout + write P' to LDS (bf16, row-major rows = q-within-64).
  const float* Ub = drop_u + (size_t)b * (SDIM * SDIM);
  const float rs = 1.0f / 0.9f;
  #pragma unroll
  for (int n = 0; n < 16; ++n) {
    #pragma unroll
    for (int j = 0; j < 4; ++j) {
      const int r = quad * 4 + j;
      float u = Ub[(q0 + r) * SDIM + n * 16 + lid];
      float pv = (u >= 0.1f) ? (sacc[n][j] * rs) : 0.0f;
      KP[(w * 16 + r) * LDSP + n * 16 + lid] = (bf16_t)pv;
    }
  }
  __syncthreads();

  // Phase B: out^T[D][q] = sum_k vT[D][k] * P'[q][k].
  const bf16_t* vTb = vT + (size_t)b * (SDIM * SDIM);
  f32x4 oacc[16];
  #pragma unroll
  for (int m = 0; m < 16; ++m) oacc[m] = (f32x4){0.f, 0.f, 0.f, 0.f};

  #pragma unroll 2
  for (int k0 = 0; k0 < 8; ++k0) {
    bf16x8 pf = *(const bf16x8*)(&KP[(w * 16 + lid) * LDSP + k0 * 32 + quad * 8]);
    #pragma unroll
    for (int m = 0; m < 16; ++m) {
      bf16x8 af = *(const bf16x8*)(vTb + (m * 16 + lid) * SDIM + k0 * 32 + quad * 8);
      oacc[m] = __builtin_amdgcn_mfma_f32_16x16x32_bf16(af, pf, oacc[m], 0, 0, 0);
    }
  }

  // Store out[b][D][q] (reference's swapaxes(1,2)); lanes contiguous in q.
  float* outbp = out + (size_t)b * (SDIM * SDIM);
  #pragma unroll
  for (int m = 0; m < 16; ++m) {
    #pragma unroll
    for (int j = 0; j < 4; ++j) {
      const int D = m * 16 + quad * 4 + j;
      outbp[D * SDIM + q0 + lid] = oacc[m][j];
    }
  }
}

extern "C" void kernel_launch(void* const* d_in, const int* in_sizes, int n_in,
                              void* d_out, int out_size, void* d_ws, size_t ws_size,
                              hipStream_t stream) {
  (void)in_sizes; (void)n_in; (void)out_size; (void)ws_size;
  const float* query    = (const float*)d_in[0];
  const float* key      = (const float*)d_in[1];
  const float* value    = (const float*)d_in[2];
  const float* drop_u   = (const float*)d_in[3];
  // d_in[4] = qk_bias: per-(b,q) constant added before softmax -> no-op.
  const float* v_weight = (const float*)d_in[5];
  const float* v_bias   = (const float*)d_in[6];
  float* out = (float*)d_out;
  bf16_t* vT = (bf16_t*)d_ws;  // needs 33,554,432 bytes of workspace

  vproj_kernel<<<dim3(1024), dim3(256), 0, stream>>>(value, v_weight, v_bias, vT);
  attn_kernel<<<dim3(1024), dim3(256), 0, stream>>>(query, key, drop_u, vT, out);
}

// Round 2
// 498.885 us; speedup vs baseline: 1.0123x; 1.0123x over previous
//
#include <hip/hip_runtime.h>

// S = 256. Out[b][D][q] = sum_k softmax_k(QK^T/16)[b,q,k]*keep[b,q,k]*v[b,k,D]
// qk_bias is a per-(b,q) additive constant before softmax -> softmax-invariant -> skipped.
// d_ws holds vT[b][D][k] as bf16: 256^3 * 2 = 33,554,432 bytes.

#define SDIM 256
#define LDSP 264  // padded LDS row stride (elements); 264*2=528B, 16B-aligned

typedef __bf16 bf16_t;
typedef __bf16 bf16x8 __attribute__((ext_vector_type(8)));
typedef __bf16 bf16x4 __attribute__((ext_vector_type(4)));
typedef float f32x4 __attribute__((ext_vector_type(4)));

__device__ inline bf16x8 cvt8(float4 a, float4 b) {
  bf16x8 r;
  r[0] = (bf16_t)a.x; r[1] = (bf16_t)a.y; r[2] = (bf16_t)a.z; r[3] = (bf16_t)a.w;
  r[4] = (bf16_t)b.x; r[5] = (bf16_t)b.y; r[6] = (bf16_t)b.z; r[7] = (bf16_t)b.w;
  return r;
}
__device__ inline bf16x4 cvt4(float4 a) {
  bf16x4 r;
  r[0] = (bf16_t)a.x; r[1] = (bf16_t)a.y; r[2] = (bf16_t)a.z; r[3] = (bf16_t)a.w;
  return r;
}

// ---------------------------------------------------------------------------
// Kernel 1: vT[b][D][k] = sum_d W[b][d][D]*value[b][k][d] + v_bias[k][D], bf16
// grid = 256 b * 4 Dblocks; block = 256 (4 waves).
// Single 33.8KB LDS buffer reused: WT tile -> value k-slabs -> output bounce.
// ---------------------------------------------------------------------------
__global__ __launch_bounds__(256) void vproj_kernel(
    const float* __restrict__ value, const float* __restrict__ v_weight,
    const float* __restrict__ v_bias, bf16_t* __restrict__ vT)
{
  __shared__ bf16_t SH[64 * LDSP];

  const int b     = blockIdx.x >> 2;
  const int Dbase = (blockIdx.x & 3) * 64;
  const int t    = threadIdx.x;
  const int w    = t >> 6;
  const int lane = t & 63;
  const int lid  = lane & 15;
  const int quad = lane >> 4;

  const float* Wb = v_weight + (size_t)b * (SDIM * SDIM);
  const float* Vb = value    + (size_t)b * (SDIM * SDIM);

  // Early bias preload into registers (scattered loads hidden behind GEMM).
  // Lane needs bias[n*16+lid][Dbase + w*16 + quad*4 + j], n=0..15, j=0..3.
  bf16x4 biasr[16];
  {
    const float* bp = v_bias + Dbase + w * 16 + quad * 4;
    #pragma unroll
    for (int n = 0; n < 16; ++n)
      biasr[n] = cvt4(*(const float4*)(bp + (n * 16 + lid) * SDIM));
  }

  // Phase 0: stage W^T tile (bf16) into SH; cache A-fragments in registers.
  {
    const int c4 = (t & 15) * 4;
    const int r0 = t >> 4;
    for (int p = 0; p < 16; ++p) {
      const int r = p * 16 + r0;
      float4 f = *(const float4*)(Wb + r * SDIM + Dbase + c4);
      SH[(c4 + 0) * LDSP + r] = (bf16_t)f.x;
      SH[(c4 + 1) * LDSP + r] = (bf16_t)f.y;
      SH[(c4 + 2) * LDSP + r] = (bf16_t)f.z;
      SH[(c4 + 3) * LDSP + r] = (bf16_t)f.w;
    }
  }
  __syncthreads();
  bf16x8 af[8];
  #pragma unroll
  for (int d = 0; d < 8; ++d)
    af[d] = *(const bf16x8*)(&SH[(w * 16 + lid) * LDSP + d * 32 + quad * 8]);
  __syncthreads();  // all waves read WT before value slabs overwrite SH

  f32x4 acc[16];
  #pragma unroll
  for (int n = 0; n < 16; ++n) acc[n] = (f32x4){0.f, 0.f, 0.f, 0.f};

  // K-loop over 4 k-slabs of 64 rows; value staged via LDS (read once/block).
  for (int kt = 0; kt < 4; ++kt) {
    if (kt) __syncthreads();
    #pragma unroll
    for (int p = 0; p < 16; ++p) {
      const int r = p * 4 + w;  // each wave covers one full 1KB row per pass
      float4 f = *(const float4*)(Vb + (kt * 64 + r) * SDIM + lane * 4);
      *(bf16x4*)(&SH[r * LDSP + lane * 4]) = cvt4(f);
    }
    __syncthreads();
    #pragma unroll
    for (int n4 = 0; n4 < 4; ++n4) {
      const int n = kt * 4 + n4;
      #pragma unroll
      for (int d = 0; d < 8; ++d) {
        bf16x8 bfr = *(const bf16x8*)(&SH[(n4 * 16 + lid) * LDSP + d * 32 + quad * 8]);
        acc[n] = __builtin_amdgcn_mfma_f32_16x16x32_bf16(af[d], bfr, acc[n], 0, 0, 0);
      }
    }
  }
  __syncthreads();

  // Epilogue: add bias, dump to SH (bf16), then full-line coalesced stores.
  #pragma unroll
  for (int n = 0; n < 16; ++n) {
    const int k = n * 16 + lid;
    #pragma unroll
    for (int j = 0; j < 4; ++j) {
      const int Dloc = w * 16 + quad * 4 + j;
      SH[Dloc * LDSP + k] = (bf16_t)(acc[n][j] + (float)biasr[n][j]);
    }
  }
  __syncthreads();
  bf16_t* outb = vT + (size_t)b * (SDIM * SDIM) + (size_t)Dbase * SDIM;
  #pragma unroll
  for (int p = 0; p < 8; ++p) {
    const int r = p * 8 + (t >> 5);  // 8 rows (4KB contiguous) per pass
    const int c = (t & 31) * 8;
    bf16x8 h = *(const bf16x8*)(&SH[r * LDSP + c]);
    *(bf16x8*)(outb + r * SDIM + c) = h;
  }
}

// ---------------------------------------------------------------------------
// Kernel 2: fused attention. grid = 256 b * 4 q-tiles; block = 256 (4 waves).
// Phase A: S = QK^T with K slabs staged in LDS (bf16). Softmax in registers.
// Dropout, P -> KP. Phase B: out^T[D][q] = vT * P^T with vT 32-row slabs
// staged in a second LDS buffer (coalesced, shared by all waves).
// ---------------------------------------------------------------------------
__global__ __launch_bounds__(256) void attn_kernel(
    const float* __restrict__ query, const float* __restrict__ key,
    const float* __restrict__ drop_u, const bf16_t* __restrict__ vT,
    float* __restrict__ out)
{
  __shared__ bf16_t KP[64 * LDSP];  // K tiles, then P (33.8 KB)
  __shared__ bf16_t VS[32 * LDSP];  // vT slab staging (16.9 KB)

  const int b  = blockIdx.x >> 2;
  const int qt = blockIdx.x & 3;
  const int t    = threadIdx.x;
  const int w    = t >> 6;
  const int lane = t & 63;
  const int lid  = lane & 15;
  const int quad = lane >> 4;
  const int q0 = qt * 64 + w * 16;

  const float* Qb = query + (size_t)b * (SDIM * SDIM);
  const float* Kb = key   + (size_t)b * (SDIM * SDIM);

  // Preload Q fragments (A-layout: row = q0+lid, k = d*32 + quad*8 + j).
  bf16x8 qf[8];
  #pragma unroll
  for (int d = 0; d < 8; ++d) {
    const float* p = Qb + (q0 + lid) * SDIM + d * 32 + quad * 8;
    float4 a = *(const float4*)(p);
    float4 c = *(const float4*)(p + 4);
    qf[d] = cvt8(a, c);
  }

  f32x4 sacc[16];
  #pragma unroll
  for (int n = 0; n < 16; ++n) sacc[n] = (f32x4){0.f, 0.f, 0.f, 0.f};

  // Phase A: S[q][k], K staged per 64-row slab (coalesced row loads).
  for (int kt = 0; kt < 4; ++kt) {
    if (kt) __syncthreads();
    #pragma unroll
    for (int p = 0; p < 16; ++p) {
      const int r = p * 4 + w;
      float4 f = *(const float4*)(Kb + (kt * 64 + r) * SDIM + lane * 4);
      *(bf16x4*)(&KP[r * LDSP + lane * 4]) = cvt4(f);
    }
    __syncthreads();
    #pragma unroll
    for (int n4 = 0; n4 < 4; ++n4) {
      const int n = kt * 4 + n4;
      #pragma unroll
      for (int d = 0; d < 8; ++d) {
        bf16x8 bfr = *(const bf16x8*)(&KP[(n4 * 16 + lid) * LDSP + d * 32 + quad * 8]);
        sacc[n] = __builtin_amdgcn_mfma_f32_16x16x32_bf16(qf[d], bfr, sacc[n], 0, 0, 0);
      }
    }
  }
  __syncthreads();

  // Softmax per q-row (C-layout: row = quad*4+j, col = n*16+lid).
  #pragma unroll
  for (int j = 0; j < 4; ++j) {
    float mx = sacc[0][j];
    #pragma unroll
    for (int n = 1; n < 16; ++n) mx = fmaxf(mx, sacc[n][j]);
    #pragma unroll
    for (int off = 8; off >= 1; off >>= 1) mx = fmaxf(mx, __shfl_xor(mx, off, 64));
    float sum = 0.f;
    #pragma unroll
    for (int n = 0; n < 16; ++n) {
      float e = __expf((sacc[n][j] - mx) * 0.0625f);
      sacc[n][j] = e;
      sum += e;
    }
    #pragma unroll
    for (int off = 8; off >= 1; off >>= 1) sum += __shfl_xor(sum, off, 64);
    float inv = 1.0f / sum;
    #pragma unroll
    for (int n = 0; n < 16; ++n) sacc[n][j] *= inv;
  }

  // Dropout + write P to LDS (row = q-within-64).
  const float* Ub = drop_u + (size_t)b * (SDIM * SDIM);
  const float rs = 1.0f / 0.9f;
  #pragma unroll
  for (int n = 0; n < 16; ++n) {
    #pragma unroll
    for (int j = 0; j < 4; ++j) {
      const int r = quad * 4 + j;
      float u = Ub[(q0 + r) * SDIM + n * 16 + lid];
      float pv = (u >= 0.1f) ? (sacc[n][j] * rs) : 0.0f;
      KP[(w * 16 + r) * LDSP + n * 16 + lid] = (bf16_t)pv;
    }
  }
  __syncthreads();

  // Phase B: out^T[D][q] = sum_k vT[D][k] * P[q][k]; vT via 32-row LDS slabs.
  const bf16_t* vTb = vT + (size_t)b * (SDIM * SDIM);
  f32x4 oacc[16];
  #pragma unroll
  for (int m = 0; m < 16; ++m) oacc[m] = (f32x4){0.f, 0.f, 0.f, 0.f};

  for (int Dt = 0; Dt < 8; ++Dt) {
    if (Dt) __syncthreads();
    #pragma unroll
    for (int p = 0; p < 4; ++p) {
      const int r = p * 8 + (t >> 5);  // 8 rows (4KB contiguous) per pass
      const int c = (t & 31) * 8;
      bf16x8 h = *(const bf16x8*)(vTb + (Dt * 32 + r) * SDIM + c);
      *(bf16x8*)(&VS[r * LDSP + c]) = h;
    }
    __syncthreads();
    #pragma unroll
    for (int k0 = 0; k0 < 8; ++k0) {
      bf16x8 pf = *(const bf16x8*)(&KP[(w * 16 + lid) * LDSP + k0 * 32 + quad * 8]);
      #pragma unroll
      for (int ml = 0; ml < 2; ++ml) {
        bf16x8 afv = *(const bf16x8*)(&VS[(ml * 16 + lid) * LDSP + k0 * 32 + quad * 8]);
        oacc[Dt * 2 + ml] =
            __builtin_amdgcn_mfma_f32_16x16x32_bf16(afv, pf, oacc[Dt * 2 + ml], 0, 0, 0);
      }
    }
  }

  // Store out[b][D][q]; 16 contiguous f32 per quad-row = full 64B lines.
  float* outbp = out + (size_t)b * (SDIM * SDIM);
  #pragma unroll
  for (int Dt = 0; Dt < 8; ++Dt) {
    #pragma unroll
    for (int ml = 0; ml < 2; ++ml) {
      #pragma unroll
      for (int j = 0; j < 4; ++j) {
        const int D = Dt * 32 + ml * 16 + quad * 4 + j;
        outbp[D * SDIM + q0 + lid] = oacc[Dt * 2 + ml][j];
      }
    }
  }
}

extern "C" void kernel_launch(void* const* d_in, const int* in_sizes, int n_in,
                              void* d_out, int out_size, void* d_ws, size_t ws_size,
                              hipStream_t stream) {
  (void)in_sizes; (void)n_in; (void)out_size; (void)ws_size;
  const float* query    = (const float*)d_in[0];
  const float* key      = (const float*)d_in[1];
  const float* value    = (const float*)d_in[2];
  const float* drop_u   = (const float*)d_in[3];
  // d_in[4] = qk_bias: softmax-invariant -> skipped.
  const float* v_weight = (const float*)d_in[5];
  const float* v_bias   = (const float*)d_in[6];
  float* out = (float*)d_out;
  bf16_t* vT = (bf16_t*)d_ws;  // 33,554,432 bytes of workspace

  vproj_kernel<<<dim3(1024), dim3(256), 0, stream>>>(value, v_weight, v_bias, vT);
  attn_kernel<<<dim3(1024), dim3(256), 0, stream>>>(query, key, drop_u, vT, out);
}

// Round 3
// 340.742 us; speedup vs baseline: 1.4821x; 1.4641x over previous
//
#include <hip/hip_runtime.h>

// S = 256. Out[b][D][q] = sum_k softmax_k(QK^T/16)[b,q,k]*keep[b,q,k]*v[b,k,D]
// qk_bias is a per-(b,q) additive constant before softmax -> softmax-invariant -> skipped.
// d_ws holds vT[b][D][k] as bf16: 256^3 * 2 = 33,554,432 bytes.
//
// Round-3 structure: software-pipelined staging (issue slab s+1 loads -> regs
// before the barrier; MFMA slab s from LDS buf s&1; write regs -> buf (s+1)&1
// after), one barrier per slab. XCD swizzle co-locates the 4 sub-blocks of a
// batch b on one XCD for L2 reuse of value/K/vT.

#define SDIM 256
#define LDSP 264  // padded LDS row stride (elements); 264*2=528B, 16B-aligned

typedef __bf16 bf16_t;
typedef __bf16 bf16x8 __attribute__((ext_vector_type(8)));
typedef __bf16 bf16x4 __attribute__((ext_vector_type(4)));
typedef float f32x4 __attribute__((ext_vector_type(4)));

__device__ inline bf16x8 cvt8(float4 a, float4 b) {
  bf16x8 r;
  r[0] = (bf16_t)a.x; r[1] = (bf16_t)a.y; r[2] = (bf16_t)a.z; r[3] = (bf16_t)a.w;
  r[4] = (bf16_t)b.x; r[5] = (bf16_t)b.y; r[6] = (bf16_t)b.z; r[7] = (bf16_t)b.w;
  return r;
}
__device__ inline bf16x4 cvt4(float4 a) {
  bf16x4 r;
  r[0] = (bf16_t)a.x; r[1] = (bf16_t)a.y; r[2] = (bf16_t)a.z; r[3] = (bf16_t)a.w;
  return r;
}

// ---------------------------------------------------------------------------
// Kernel 1: vT[b][D][k] = sum_d W[b][d][D]*value[b][k][d] + v_bias[k][D], bf16
// grid = 1024 (XCD-swizzled (b, Dblk)); block = 256 (4 waves).
// SH reused: WT tile -> double-buffered 32-row value slabs -> output bounce.
// ---------------------------------------------------------------------------
__global__ __launch_bounds__(256) void vproj_kernel(
    const float* __restrict__ value, const float* __restrict__ v_weight,
    const float* __restrict__ v_bias, bf16_t* __restrict__ vT)
{
  __shared__ bf16_t SH[64 * LDSP];

  // XCD swizzle: all 4 Dblks of a given b share xcd = b & 7.
  const int pidx = blockIdx.x;
  const int xcd  = pidx & 7;
  const int jj   = pidx >> 3;
  const int Dblk = jj & 3;
  const int b    = xcd + ((jj >> 2) << 3);
  const int Dbase = Dblk * 64;

  const int t    = threadIdx.x;
  const int w    = t >> 6;
  const int lane = t & 63;
  const int lid  = lane & 15;
  const int quad = lane >> 4;

  const float* Wb = v_weight + (size_t)b * (SDIM * SDIM);
  const float* Vb = value    + (size_t)b * (SDIM * SDIM);

  // Issue slab-0 value loads first (in flight during WT staging).
  float4 vr[8];
  #pragma unroll
  for (int p2 = 0; p2 < 8; ++p2)
    vr[p2] = *(const float4*)(Vb + (p2 * 4 + w) * SDIM + lane * 4);

  // Bias preload (scattered, hidden behind the GEMM).
  bf16x4 biasr[16];
  {
    const float* bp = v_bias + Dbase + w * 16 + quad * 4;
    #pragma unroll
    for (int n = 0; n < 16; ++n)
      biasr[n] = cvt4(*(const float4*)(bp + (n * 16 + lid) * SDIM));
  }

  // Stage W^T tile (bf16) into SH; cache A-fragments in registers.
  {
    const int c4 = (t & 15) * 4;
    const int r0 = t >> 4;
    #pragma unroll
    for (int p = 0; p < 16; ++p) {
      const int r = p * 16 + r0;
      float4 f = *(const float4*)(Wb + r * SDIM + Dbase + c4);
      SH[(c4 + 0) * LDSP + r] = (bf16_t)f.x;
      SH[(c4 + 1) * LDSP + r] = (bf16_t)f.y;
      SH[(c4 + 2) * LDSP + r] = (bf16_t)f.z;
      SH[(c4 + 3) * LDSP + r] = (bf16_t)f.w;
    }
  }
  __syncthreads();
  bf16x8 af[8];
  #pragma unroll
  for (int d = 0; d < 8; ++d)
    af[d] = *(const bf16x8*)(&SH[(w * 16 + lid) * LDSP + d * 32 + quad * 8]);
  __syncthreads();  // all waves read WT before value slabs overwrite SH

  // Write slab 0 into buffer 0.
  #pragma unroll
  for (int p2 = 0; p2 < 8; ++p2)
    *(bf16x4*)(&SH[(p2 * 4 + w) * LDSP + lane * 4]) = cvt4(vr[p2]);

  f32x4 acc[16];
  #pragma unroll
  for (int n = 0; n < 16; ++n) acc[n] = (f32x4){0.f, 0.f, 0.f, 0.f};

  // Pipelined K-loop: 8 slabs of 32 k-rows, double-buffered in SH halves.
  for (int s = 0; s < 8; ++s) {
    if (s < 7) {
      #pragma unroll
      for (int p2 = 0; p2 < 8; ++p2)
        vr[p2] = *(const float4*)(Vb + ((s + 1) * 32 + p2 * 4 + w) * SDIM + lane * 4);
    }
    __syncthreads();  // buffer s&1 ready; prior readers of buffer (s+1)&1 done
    const int rb = (s & 1) * 32;
    #pragma unroll
    for (int n4 = 0; n4 < 2; ++n4) {
      const int n = s * 2 + n4;
      #pragma unroll
      for (int d = 0; d < 8; ++d) {
        bf16x8 bfr = *(const bf16x8*)(&SH[(rb + n4 * 16 + lid) * LDSP + d * 32 + quad * 8]);
        acc[n] = __builtin_amdgcn_mfma_f32_16x16x32_bf16(af[d], bfr, acc[n], 0, 0, 0);
      }
    }
    if (s < 7) {
      const int wb = ((s + 1) & 1) * 32;
      #pragma unroll
      for (int p2 = 0; p2 < 8; ++p2)
        *(bf16x4*)(&SH[(wb + p2 * 4 + w) * LDSP + lane * 4]) = cvt4(vr[p2]);
    }
  }
  __syncthreads();

  // Epilogue: add bias, bounce via SH, full-line coalesced stores.
  #pragma unroll
  for (int n = 0; n < 16; ++n) {
    const int k = n * 16 + lid;
    #pragma unroll
    for (int j = 0; j < 4; ++j) {
      const int Dloc = w * 16 + quad * 4 + j;
      SH[Dloc * LDSP + k] = (bf16_t)(acc[n][j] + (float)biasr[n][j]);
    }
  }
  __syncthreads();
  bf16_t* outb = vT + (size_t)b * (SDIM * SDIM) + (size_t)Dbase * SDIM;
  #pragma unroll
  for (int p = 0; p < 8; ++p) {
    const int r = p * 8 + (t >> 5);
    const int c = (t & 31) * 8;
    bf16x8 h = *(const bf16x8*)(&SH[r * LDSP + c]);
    *(bf16x8*)(outb + r * SDIM + c) = h;
  }
}

// ---------------------------------------------------------------------------
// Kernel 2: fused attention. grid = 1024 (XCD-swizzled (b, qt)); block = 256.
// Phase A: S = QK^T, K in 32-row slabs double-buffered in KP halves (pipelined).
// Softmax in registers; P -> KP; dropout via coalesced in-LDS RMW pass.
// Phase B: out^T[D][q] = vT * P^T, vT in 16-row slabs double-buffered in VS.
// ---------------------------------------------------------------------------
__global__ __launch_bounds__(256) void attn_kernel(
    const float* __restrict__ query, const float* __restrict__ key,
    const float* __restrict__ drop_u, const bf16_t* __restrict__ vT,
    float* __restrict__ out)
{
  __shared__ bf16_t KP[64 * LDSP];      // K slabs (2x32), then P (33.8 KB)
  __shared__ bf16_t VS[2 * 16 * LDSP];  // vT slab double buffer (16.9 KB)

  const int pidx = blockIdx.x;
  const int xcd  = pidx & 7;
  const int jj   = pidx >> 3;
  const int qt   = jj & 3;
  const int b    = xcd + ((jj >> 2) << 3);

  const int t    = threadIdx.x;
  const int w    = t >> 6;
  const int lane = t & 63;
  const int lid  = lane & 15;
  const int quad = lane >> 4;
  const int q0 = qt * 64 + w * 16;

  const float* Qb = query + (size_t)b * (SDIM * SDIM);
  const float* Kb = key   + (size_t)b * (SDIM * SDIM);

  // Issue K slab-0 loads first.
  float4 kr[8];
  #pragma unroll
  for (int p2 = 0; p2 < 8; ++p2)
    kr[p2] = *(const float4*)(Kb + (p2 * 4 + w) * SDIM + lane * 4);

  // Q fragments (A-layout: row = q0+lid, k = d*32 + quad*8 + j).
  bf16x8 qf[8];
  #pragma unroll
  for (int d = 0; d < 8; ++d) {
    const float* p = Qb + (q0 + lid) * SDIM + d * 32 + quad * 8;
    float4 a = *(const float4*)(p);
    float4 c = *(const float4*)(p + 4);
    qf[d] = cvt8(a, c);
  }

  // Write slab 0 into KP buffer 0.
  #pragma unroll
  for (int p2 = 0; p2 < 8; ++p2)
    *(bf16x4*)(&KP[(p2 * 4 + w) * LDSP + lane * 4]) = cvt4(kr[p2]);

  f32x4 sacc[16];
  #pragma unroll
  for (int n = 0; n < 16; ++n) sacc[n] = (f32x4){0.f, 0.f, 0.f, 0.f};

  // Phase A: pipelined over 8 slabs of 32 key rows.
  for (int s = 0; s < 8; ++s) {
    if (s < 7) {
      #pragma unroll
      for (int p2 = 0; p2 < 8; ++p2)
        kr[p2] = *(const float4*)(Kb + ((s + 1) * 32 + p2 * 4 + w) * SDIM + lane * 4);
    }
    __syncthreads();
    const int rb = (s & 1) * 32;
    #pragma unroll
    for (int n4 = 0; n4 < 2; ++n4) {
      const int n = s * 2 + n4;
      #pragma unroll
      for (int d = 0; d < 8; ++d) {
        bf16x8 bfr = *(const bf16x8*)(&KP[(rb + n4 * 16 + lid) * LDSP + d * 32 + quad * 8]);
        sacc[n] = __builtin_amdgcn_mfma_f32_16x16x32_bf16(qf[d], bfr, sacc[n], 0, 0, 0);
      }
    }
    if (s < 7) {
      const int wb = ((s + 1) & 1) * 32;
      #pragma unroll
      for (int p2 = 0; p2 < 8; ++p2)
        *(bf16x4*)(&KP[(wb + p2 * 4 + w) * LDSP + lane * 4]) = cvt4(kr[p2]);
    }
  }
  __syncthreads();  // phase A reads done; KP free for P

  // Softmax per q-row (C-layout: row = quad*4+j, col = n*16+lid).
  #pragma unroll
  for (int j = 0; j < 4; ++j) {
    float mx = sacc[0][j];
    #pragma unroll
    for (int n = 1; n < 16; ++n) mx = fmaxf(mx, sacc[n][j]);
    #pragma unroll
    for (int off = 8; off >= 1; off >>= 1) mx = fmaxf(mx, __shfl_xor(mx, off, 64));
    float sum = 0.f;
    #pragma unroll
    for (int n = 0; n < 16; ++n) {
      float e = __expf((sacc[n][j] - mx) * 0.0625f);
      sacc[n][j] = e;
      sum += e;
    }
    #pragma unroll
    for (int off = 8; off >= 1; off >>= 1) sum += __shfl_xor(sum, off, 64);
    float inv = 1.0f / sum;
    #pragma unroll
    for (int n = 0; n < 16; ++n) sacc[n][j] *= inv;
  }

  // Issue dropout-noise loads (coalesced float4; consumed after the barrier).
  // Thread t owns row = t>>2 (q within tile), cols i*16 + (t&3)*4.
  float4 ur[16];
  {
    const float* Ub = drop_u + (size_t)b * (SDIM * SDIM) + (size_t)(qt * 64 + (t >> 2)) * SDIM;
    #pragma unroll
    for (int i = 0; i < 16; ++i)
      ur[i] = *(const float4*)(Ub + i * 16 + (t & 3) * 4);
  }

  // Write P (no dropout yet) to KP rows = q-within-tile.
  #pragma unroll
  for (int n = 0; n < 16; ++n) {
    #pragma unroll
    for (int j = 0; j < 4; ++j) {
      const int r = quad * 4 + j;
      KP[(w * 16 + r) * LDSP + n * 16 + lid] = (bf16_t)sacc[n][j];
    }
  }
  __syncthreads();

  // Dropout: in-LDS RMW with the preloaded noise (latency already hidden).
  {
    const int r  = t >> 2;
    const float rs = 1.0f / 0.9f;
    #pragma unroll
    for (int i = 0; i < 16; ++i) {
      const int c = i * 16 + (t & 3) * 4;
      bf16x4 pv = *(const bf16x4*)(&KP[r * LDSP + c]);
      pv[0] = (ur[i].x >= 0.1f) ? (bf16_t)((float)pv[0] * rs) : (bf16_t)0.f;
      pv[1] = (ur[i].y >= 0.1f) ? (bf16_t)((float)pv[1] * rs) : (bf16_t)0.f;
      pv[2] = (ur[i].z >= 0.1f) ? (bf16_t)((float)pv[2] * rs) : (bf16_t)0.f;
      pv[3] = (ur[i].w >= 0.1f) ? (bf16_t)((float)pv[3] * rs) : (bf16_t)0.f;
      *(bf16x4*)(&KP[r * LDSP + c]) = pv;
    }
  }
  __syncthreads();

  // Cache P fragments for this wave (independent of the D-slab loop).
  bf16x8 pf[8];
  #pragma unroll
  for (int k0 = 0; k0 < 8; ++k0)
    pf[k0] = *(const bf16x8*)(&KP[(w * 16 + lid) * LDSP + k0 * 32 + quad * 8]);

  // Phase B: pipelined over 16 slabs of 16 D-rows of vT (double-buffered VS).
  const bf16_t* vTb = vT + (size_t)b * (SDIM * SDIM);
  f32x4 oacc[16];
  #pragma unroll
  for (int m = 0; m < 16; ++m) oacc[m] = (f32x4){0.f, 0.f, 0.f, 0.f};

  bf16x8 tr[2];
  #pragma unroll
  for (int p3 = 0; p3 < 2; ++p3)
    tr[p3] = *(const bf16x8*)(vTb + (p3 * 8 + (t >> 5)) * SDIM + (t & 31) * 8);
  #pragma unroll
  for (int p3 = 0; p3 < 2; ++p3)
    *(bf16x8*)(&VS[(p3 * 8 + (t >> 5)) * LDSP + (t & 31) * 8]) = tr[p3];

  for (int s = 0; s < 16; ++s) {
    if (s < 15) {
      #pragma unroll
      for (int p3 = 0; p3 < 2; ++p3)
        tr[p3] = *(const bf16x8*)(vTb + ((s + 1) * 16 + p3 * 8 + (t >> 5)) * SDIM + (t & 31) * 8);
    }
    __syncthreads();
    const int rb = (s & 1) * 16;
    #pragma unroll
    for (int k0 = 0; k0 < 8; ++k0) {
      bf16x8 afv = *(const bf16x8*)(&VS[(rb + lid) * LDSP + k0 * 32 + quad * 8]);
      oacc[s] = __builtin_amdgcn_mfma_f32_16x16x32_bf16(afv, pf[k0], oacc[s], 0, 0, 0);
    }
    if (s < 15) {
      const int wb = ((s + 1) & 1) * 16;
      #pragma unroll
      for (int p3 = 0; p3 < 2; ++p3)
        *(bf16x8*)(&VS[(wb + p3 * 8 + (t >> 5)) * LDSP + (t & 31) * 8]) = tr[p3];
    }
  }

  // Store out[b][D][q]; 16 contiguous f32 per quad-row.
  float* outbp = out + (size_t)b * (SDIM * SDIM);
  #pragma unroll
  for (int s = 0; s < 16; ++s) {
    #pragma unroll
    for (int j = 0; j < 4; ++j) {
      const int D = s * 16 + quad * 4 + j;
      outbp[D * SDIM + q0 + lid] = oacc[s][j];
    }
  }
}

extern "C" void kernel_launch(void* const* d_in, const int* in_sizes, int n_in,
                              void* d_out, int out_size, void* d_ws, size_t ws_size,
                              hipStream_t stream) {
  (void)in_sizes; (void)n_in; (void)out_size; (void)ws_size;
  const float* query    = (const float*)d_in[0];
  const float* key      = (const float*)d_in[1];
  const float* value    = (const float*)d_in[2];
  const float* drop_u   = (const float*)d_in[3];
  // d_in[4] = qk_bias: softmax-invariant -> skipped.
  const float* v_weight = (const float*)d_in[5];
  const float* v_bias   = (const float*)d_in[6];
  float* out = (float*)d_out;
  bf16_t* vT = (bf16_t*)d_ws;  // 33,554,432 bytes of workspace

  vproj_kernel<<<dim3(1024), dim3(256), 0, stream>>>(value, v_weight, v_bias, vT);
  attn_kernel<<<dim3(1024), dim3(256), 0, stream>>>(query, key, drop_u, vT, out);
}